// Round 4
// baseline (147.697 us; speedup 1.0000x reference)
//
#include <hip/hip_runtime.h>
#include <hip/hip_bf16.h>

#define D 128
#define MARGIN 0.5f
#define NSPLIT 64      // j-splits; each wave: 64 rows x 128 cols
#define NCHUNK 8       // 128 cols / 16

typedef __attribute__((ext_vector_type(8))) short bf16x8;
typedef __attribute__((ext_vector_type(4))) float f32x4;

// ---------------- prep: bf16 convert + sq + init ----------------
__global__ void prep_kernel(const float* __restrict__ x,
                            float* __restrict__ sq,
                            unsigned* __restrict__ ap,
                            unsigned* __restrict__ an,
                            __hip_bfloat16* __restrict__ xb,
                            float* __restrict__ out, int n) {
    int tid = threadIdx.x;
    int row = blockIdx.x * 4 + (tid >> 6);
    int lane = tid & 63;
    const float2* xr = (const float2*)(x + (size_t)row * D);
    float2 v = xr[lane];
    __hip_bfloat162 b2;
    b2.x = __float2bfloat16(v.x);
    b2.y = __float2bfloat16(v.y);
    ((__hip_bfloat162*)(xb + (size_t)row * D))[lane] = b2;
    float s = v.x * v.x + v.y * v.y;
    #pragma unroll
    for (int o = 32; o > 0; o >>= 1) s += __shfl_xor(s, o, 64);
    if (lane == 0) {
        sq[row] = s;
        ap[row] = 0u;            // dist >= 0 -> 0 is a valid -inf for max
        an[row] = 0x7F800000u;   // +inf bits
    }
    if (blockIdx.x == 0 && tid == 0) *out = 0.0f;
}

// ---------------- gram: LDS-free, register-resident MFMA ----------------
// One wave = 64 rows x 128 cols. A-frags register-resident; the 4 waves of a
// block share istrip -> A rows L1-hot. B streamed from L2 in 16-col chunks,
// register double-buffered. No __syncthreads. Grid 2048 blocks -> ~50% occ.
__launch_bounds__(256, 2)
__global__ void gram_kernel(const __hip_bfloat16* __restrict__ xb,
                            const float* __restrict__ sq,
                            const int* __restrict__ tgt,
                            unsigned* __restrict__ ap,
                            unsigned* __restrict__ an, int n) {
    const int tid  = threadIdx.x;
    const int wid  = tid >> 6;
    const int lane = tid & 63;
    const int quad = lane >> 4;
    const int l    = lane & 15;
    const int gw     = blockIdx.x * 4 + wid;   // 0..8191
    const int istrip = gw >> 6;                // 0..127 (waves in a block share)
    const int jsplit = gw & 63;                // 0..63
    const int i0 = istrip * 64;
    const int j0 = jsplit * (16 * NCHUNK);     // 128-col window

    // A fragments: lane holds A[m = l][k = quad*8 + j] for each 16-row tile
    bf16x8 afrag[4][4];
    {
        const __hip_bfloat16* abase = xb + (size_t)(i0 + l) * D + quad * 8;
        #pragma unroll
        for (int mt = 0; mt < 4; ++mt)
            #pragma unroll
            for (int ks = 0; ks < 4; ++ks)
                afrag[mt][ks] = *(const bf16x8*)(abase + (size_t)mt * 16 * D + ks * 32);
    }

    // row labels: C/D row = quad*4 + reg within each 16-row tile
    int li[4][4];
    #pragma unroll
    for (int mt = 0; mt < 4; ++mt)
        #pragma unroll
        for (int reg = 0; reg < 4; ++reg)
            li[mt][reg] = tgt[i0 + mt * 16 + quad * 4 + reg];

    // running hardest pos/neg in t-space (t = sq_j - 2*dot); add sq_i at end
    float lap[16], lan[16];
    #pragma unroll
    for (int k = 0; k < 16; ++k) { lap[k] = -1e30f; lan[k] = 1e30f; }

    const __hip_bfloat16* bbase = xb + (size_t)(j0 + l) * D + quad * 8;

    bf16x8 bf[2][4];
    float  sj[2];
    int    tj[2];

    #define LOADB(buf, c)                                                   \
        do {                                                                \
            const __hip_bfloat16* p_ = bbase + (size_t)(c) * 16 * D;        \
            bf[buf][0] = *(const bf16x8*)(p_);                              \
            bf[buf][1] = *(const bf16x8*)(p_ + 32);                         \
            bf[buf][2] = *(const bf16x8*)(p_ + 64);                         \
            bf[buf][3] = *(const bf16x8*)(p_ + 96);                         \
            sj[buf] = sq[j0 + (c) * 16 + l];                                \
            tj[buf] = tgt[j0 + (c) * 16 + l];                               \
        } while (0)

    #define COMPUTE(buf)                                                    \
        do {                                                                \
            f32x4 acc[4];                                                   \
            _Pragma("unroll")                                               \
            for (int mt = 0; mt < 4; ++mt) acc[mt] = (f32x4){0.f,0.f,0.f,0.f}; \
            _Pragma("unroll")                                               \
            for (int ks = 0; ks < 4; ++ks)                                  \
                _Pragma("unroll")                                           \
                for (int mt = 0; mt < 4; ++mt)                              \
                    acc[mt] = __builtin_amdgcn_mfma_f32_16x16x32_bf16(      \
                        afrag[mt][ks], bf[buf][ks], acc[mt], 0, 0, 0);      \
            float sjc = sj[buf]; int tjc = tj[buf];                         \
            _Pragma("unroll")                                               \
            for (int mt = 0; mt < 4; ++mt)                                  \
                _Pragma("unroll")                                           \
                for (int reg = 0; reg < 4; ++reg) {                         \
                    float t = fmaf(-2.0f, acc[mt][reg], sjc);               \
                    bool same = (li[mt][reg] == tjc);                       \
                    lap[mt*4+reg] = fmaxf(lap[mt*4+reg], same ? t : -1e30f);\
                    lan[mt*4+reg] = fminf(lan[mt*4+reg], same ? 1e30f : t); \
                }                                                           \
        } while (0)

    LOADB(0, 0);
    #pragma unroll
    for (int c = 0; c < NCHUNK; c += 2) {
        LOADB(1, c + 1);
        COMPUTE(0);
        if (c < NCHUNK - 2) LOADB(0, c + 2);
        COMPUTE(1);
    }
    #undef LOADB
    #undef COMPUTE

    // reduce across the 16 column-lanes (xor<16 stays within quad group)
    #pragma unroll
    for (int mt = 0; mt < 4; ++mt)
        #pragma unroll
        for (int reg = 0; reg < 4; ++reg) {
            float p = lap[mt*4+reg], q = lan[mt*4+reg];
            #pragma unroll
            for (int o = 1; o < 16; o <<= 1) {
                p = fmaxf(p, __shfl_xor(p, o, 64));
                q = fminf(q, __shfl_xor(q, o, 64));
            }
            if (l == mt * 4 + reg) {   // one writer lane per quad
                int gi = i0 + mt * 16 + quad * 4 + reg;
                float s = sq[gi];
                atomicMax(&ap[gi], __float_as_uint(fmaxf(s + p, 0.0f)));
                atomicMin(&an[gi], __float_as_uint(fmaxf(s + q, 0.0f)));
            }
        }
}

// ---------------- final: sum relu(ap - an + margin) ----------------
__global__ void final_kernel(const unsigned* __restrict__ ap,
                             const unsigned* __restrict__ an,
                             float* __restrict__ out, int n) {
    int i = blockIdx.x * blockDim.x + threadIdx.x;
    float v = 0.f;
    if (i < n) {
        float p = __uint_as_float(ap[i]);
        float q = __uint_as_float(an[i]);
        v = fmaxf(p - q + MARGIN, 0.0f);
    }
    #pragma unroll
    for (int o = 32; o > 0; o >>= 1) v += __shfl_xor(v, o, 64);
    __shared__ float ws[4];
    int lane = threadIdx.x & 63, w = threadIdx.x >> 6;
    if (lane == 0) ws[w] = v;
    __syncthreads();
    if (threadIdx.x == 0) atomicAdd(out, ws[0] + ws[1] + ws[2] + ws[3]);
}

extern "C" void kernel_launch(void* const* d_in, const int* in_sizes, int n_in,
                              void* d_out, int out_size, void* d_ws, size_t ws_size,
                              hipStream_t stream) {
    const float* x   = (const float*)d_in[0];
    const int*   tgt = (const int*)d_in[1];
    float* out = (float*)d_out;
    const int n = in_sizes[1];              // 8192

    float*          sq = (float*)d_ws;
    unsigned*       ap = (unsigned*)((char*)d_ws + (size_t)n * 4);
    unsigned*       an = ap + n;
    __hip_bfloat16* xb = (__hip_bfloat16*)((char*)d_ws + (size_t)n * 12);

    prep_kernel<<<n / 4, 256, 0, stream>>>(x, sq, ap, an, xb, out, n);
    gram_kernel<<<(n / 64) * NSPLIT / 4, 256, 0, stream>>>(xb, sq, tgt, ap, an, n);
    final_kernel<<<n / 256, 256, 0, stream>>>(ap, an, out, n);
}

// Round 5
// 112.924 us; speedup vs baseline: 1.3079x; 1.3079x over previous
//
#include <hip/hip_runtime.h>
#include <hip/hip_bf16.h>

#define D 128
#define MARGIN 0.5f
#define NSPLIT 16      // j-splits; block j-window = 8192/16 = 512 cols

typedef __attribute__((ext_vector_type(8))) short bf16x8;
typedef __attribute__((ext_vector_type(4))) float f32x4;

// ---------------- prep: bf16 convert + sq + init ----------------
__global__ void prep_kernel(const float* __restrict__ x,
                            float* __restrict__ sq,
                            unsigned* __restrict__ ap,
                            unsigned* __restrict__ an,
                            __hip_bfloat16* __restrict__ xb,
                            float* __restrict__ out, int n) {
    int tid = threadIdx.x;
    int row = blockIdx.x * 4 + (tid >> 6);
    int lane = tid & 63;
    const float2* xr = (const float2*)(x + (size_t)row * D);
    float2 v = xr[lane];
    __hip_bfloat162 b2;
    b2.x = __float2bfloat16(v.x);
    b2.y = __float2bfloat16(v.y);
    ((__hip_bfloat162*)(xb + (size_t)row * D))[lane] = b2;
    float s = v.x * v.x + v.y * v.y;
    #pragma unroll
    for (int o = 32; o > 0; o >>= 1) s += __shfl_xor(s, o, 64);
    if (lane == 0) {
        sq[row] = s;
        ap[row] = 0u;            // dist >= 0 -> 0 is a valid -inf for max
        an[row] = 0x7F800000u;   // +inf bits
    }
    if (blockIdx.x == 0 && tid == 0) *out = 0.0f;
}

// ---------------- gram: LDS-shared B, register A, 1-barrier pipeline -----
// Block = 4 waves = 128 i-rows (wave: 32 rows, mt=2). j-window 512 cols =
// 8 tiles of 64. B tile 64x128 bf16 = 16KB, double-buffered (32KB -> 4
// blocks/CU). XOR chunk swizzle: ds_read_b128 frags 2-way (free), staging
// conflict-free, no padding. One __syncthreads per iter; next tile loaded
// into VGPRs at iter top (latency covered by compute), ds_write after.
__launch_bounds__(256, 4)
__global__ void gram_kernel(const __hip_bfloat16* __restrict__ xb,
                            const float* __restrict__ sq,
                            const int* __restrict__ tgt,
                            unsigned* __restrict__ ap,
                            unsigned* __restrict__ an, int n) {
    __shared__ __align__(16) __hip_bfloat16 Bs[2][64 * D];

    const int tid  = threadIdx.x;
    const int wid  = tid >> 6;
    const int lane = tid & 63;
    const int quad = lane >> 4;
    const int l    = lane & 15;
    const int i0   = blockIdx.x * 128;
    const int jspan = n / NSPLIT;          // 512
    const int njit  = jspan / 64;          // 8
    const int j0    = blockIdx.y * jspan;
    const int rowbase = i0 + wid * 32;

    // A fragments, register-resident: lane holds A[m=l][k=quad*8+j]
    bf16x8 afrag[2][4];
    {
        const __hip_bfloat16* abase = xb + (size_t)(rowbase + l) * D + quad * 8;
        #pragma unroll
        for (int mt = 0; mt < 2; ++mt)
            #pragma unroll
            for (int ks = 0; ks < 4; ++ks)
                afrag[mt][ks] = *(const bf16x8*)(abase + (size_t)mt * 16 * D + ks * 32);
    }

    int li[2][4];
    #pragma unroll
    for (int mt = 0; mt < 2; ++mt)
        #pragma unroll
        for (int reg = 0; reg < 4; ++reg)
            li[mt][reg] = tgt[rowbase + mt * 16 + quad * 4 + reg];

    float lap[8], lan[8];
    #pragma unroll
    for (int k = 0; k < 8; ++k) { lap[k] = -1e30f; lan[k] = 1e30f; }

    // staging: wave wid owns chunks q = wid*256 + i*64 + lane (16B units).
    // chunk q stores global (row r=q>>4, chunk c=(q&15)^(r&15)) of the tile.
    const int q0 = wid * 256;
    float4 streg[4];
    const char* xbb = (const char*)xb;

    #define LOADTILE(jt0)                                                     \
        do {                                                                  \
            _Pragma("unroll")                                                 \
            for (int i_ = 0; i_ < 4; ++i_) {                                  \
                int q_ = q0 + i_ * 64 + lane;                                 \
                int r_ = q_ >> 4;                                             \
                int c_ = (q_ & 15) ^ (r_ & 15);                               \
                streg[i_] = *(const float4*)(xbb + (size_t)((jt0) + r_) * 256 \
                                                 + (size_t)c_ * 16);          \
            }                                                                 \
        } while (0)

    #define WRITETILE(buf)                                                    \
        do {                                                                  \
            char* b_ = (char*)&Bs[buf][0];                                    \
            _Pragma("unroll")                                                 \
            for (int i_ = 0; i_ < 4; ++i_) {                                  \
                int q_ = q0 + i_ * 64 + lane;                                 \
                *(float4*)(b_ + (size_t)q_ * 16) = streg[i_];                 \
            }                                                                 \
        } while (0)

    LOADTILE(j0);
    WRITETILE(0);
    __syncthreads();

    for (int jj = 0; jj < njit; ++jj) {
        const int cur = jj & 1;
        if (jj < njit - 1) LOADTILE(j0 + (jj + 1) * 64);   // prefetch to regs

        const char* Bb = (const char*)&Bs[cur][0];
        const int jbase = j0 + jj * 64;
        #pragma unroll
        for (int jt = 0; jt < 4; ++jt) {
            f32x4 acc0 = (f32x4){0.f, 0.f, 0.f, 0.f};
            f32x4 acc1 = (f32x4){0.f, 0.f, 0.f, 0.f};
            #pragma unroll
            for (int ks = 0; ks < 4; ++ks) {
                // frag: row jt*16+l, k-chunk ks*4+quad, swizzled
                int q = (jt * 16 + l) * 16 + ((ks * 4 + quad) ^ l);
                bf16x8 bfr = *(const bf16x8*)(Bb + (size_t)q * 16);
                acc0 = __builtin_amdgcn_mfma_f32_16x16x32_bf16(afrag[0][ks], bfr, acc0, 0, 0, 0);
                acc1 = __builtin_amdgcn_mfma_f32_16x16x32_bf16(afrag[1][ks], bfr, acc1, 0, 0, 0);
            }
            float sjc = sq[jbase + jt * 16 + l];
            int   tjc = tgt[jbase + jt * 16 + l];
            #pragma unroll
            for (int reg = 0; reg < 4; ++reg) {
                float t0 = fmaf(-2.0f, acc0[reg], sjc);
                float t1 = fmaf(-2.0f, acc1[reg], sjc);
                bool s0 = (li[0][reg] == tjc);
                bool s1 = (li[1][reg] == tjc);
                lap[reg]     = fmaxf(lap[reg],     s0 ? t0 : -1e30f);
                lan[reg]     = fminf(lan[reg],     s0 ? 1e30f : t0);
                lap[4 + reg] = fmaxf(lap[4 + reg], s1 ? t1 : -1e30f);
                lan[4 + reg] = fminf(lan[4 + reg], s1 ? 1e30f : t1);
            }
        }

        if (jj < njit - 1) WRITETILE(cur ^ 1);   // buffer free since jj-1 barrier
        __syncthreads();
    }
    #undef LOADTILE
    #undef WRITETILE

    // reduce across 16 column-lanes (xor<16 stays within quad group)
    #pragma unroll
    for (int mt = 0; mt < 2; ++mt)
        #pragma unroll
        for (int reg = 0; reg < 4; ++reg) {
            float p = lap[mt * 4 + reg], q = lan[mt * 4 + reg];
            #pragma unroll
            for (int o = 1; o < 16; o <<= 1) {
                p = fmaxf(p, __shfl_xor(p, o, 64));
                q = fminf(q, __shfl_xor(q, o, 64));
            }
            if (l == mt * 4 + reg) {   // one writer lane per quad (lanes 0..7)
                int gi = rowbase + mt * 16 + quad * 4 + reg;
                float s = sq[gi];
                atomicMax(&ap[gi], __float_as_uint(fmaxf(s + p, 0.0f)));
                atomicMin(&an[gi], __float_as_uint(fmaxf(s + q, 0.0f)));
            }
        }
}

// ---------------- final: sum relu(ap - an + margin) ----------------
__global__ void final_kernel(const unsigned* __restrict__ ap,
                             const unsigned* __restrict__ an,
                             float* __restrict__ out, int n) {
    int i = blockIdx.x * blockDim.x + threadIdx.x;
    float v = 0.f;
    if (i < n) {
        float p = __uint_as_float(ap[i]);
        float q = __uint_as_float(an[i]);
        v = fmaxf(p - q + MARGIN, 0.0f);
    }
    #pragma unroll
    for (int o = 32; o > 0; o >>= 1) v += __shfl_xor(v, o, 64);
    __shared__ float ws[4];
    int lane = threadIdx.x & 63, w = threadIdx.x >> 6;
    if (lane == 0) ws[w] = v;
    __syncthreads();
    if (threadIdx.x == 0) atomicAdd(out, ws[0] + ws[1] + ws[2] + ws[3]);
}

extern "C" void kernel_launch(void* const* d_in, const int* in_sizes, int n_in,
                              void* d_out, int out_size, void* d_ws, size_t ws_size,
                              hipStream_t stream) {
    const float* x   = (const float*)d_in[0];
    const int*   tgt = (const int*)d_in[1];
    float* out = (float*)d_out;
    const int n = in_sizes[1];              // 8192

    float*          sq = (float*)d_ws;
    unsigned*       ap = (unsigned*)((char*)d_ws + (size_t)n * 4);
    unsigned*       an = ap + n;
    __hip_bfloat16* xb = (__hip_bfloat16*)((char*)d_ws + (size_t)n * 12);

    prep_kernel<<<n / 4, 256, 0, stream>>>(x, sq, ap, an, xb, out, n);
    dim3 grid(n / 128, NSPLIT);
    gram_kernel<<<grid, 256, 0, stream>>>(xb, sq, tgt, ap, an, n);
    final_kernel<<<n / 256, 256, 0, stream>>>(ap, an, out, n);
}

// Round 6
// 90.548 us; speedup vs baseline: 1.6311x; 1.2471x over previous
//
#include <hip/hip_runtime.h>
#include <hip/hip_bf16.h>

#define D 128
#define MARGIN 0.5f
#define NSPLIT 16      // j-splits; block j-window = 8192/16 = 512 cols

typedef __attribute__((ext_vector_type(8))) short bf16x8;
typedef __attribute__((ext_vector_type(4))) float f32x4;

// ---------------- prep: bf16 convert + sq + init ----------------
__global__ void prep_kernel(const float* __restrict__ x,
                            float* __restrict__ sq,
                            unsigned* __restrict__ ap,
                            unsigned* __restrict__ an,
                            __hip_bfloat16* __restrict__ xb,
                            float* __restrict__ out, int n) {
    int tid = threadIdx.x;
    int row = blockIdx.x * 4 + (tid >> 6);
    int lane = tid & 63;
    const float2* xr = (const float2*)(x + (size_t)row * D);
    float2 v = xr[lane];
    __hip_bfloat162 b2;
    b2.x = __float2bfloat16(v.x);
    b2.y = __float2bfloat16(v.y);
    ((__hip_bfloat162*)(xb + (size_t)row * D))[lane] = b2;
    float s = v.x * v.x + v.y * v.y;
    #pragma unroll
    for (int o = 32; o > 0; o >>= 1) s += __shfl_xor(s, o, 64);
    if (lane == 0) {
        sq[row] = s;
        ap[row] = 0u;            // dist >= 0 -> 0 is a valid -inf for max
        an[row] = 0x7F800000u;   // +inf bits
    }
    if (blockIdx.x == 0 && tid == 0) *out = 0.0f;
}

// ---------------- gram: async global->LDS B, register A, 1 barrier/iter --
// Block = 4 waves = 128 i-rows (wave: 32 rows). j-window 512 = 8 tiles of 64.
// B tile 64x128 bf16 = 16KB double-buffered. Staging via
// global_load_lds width=16 (no VGPR round-trip -> no spill; R5's 103MB
// WRITE_SIZE was streg scratch spill). LDS dest is wave-uniform base +
// lane*16 (hw rule); XOR swizzle applied on the per-lane GLOBAL src addr.
// ds_read frags 2-way conflict (free), staging conflict-free, no padding.
__launch_bounds__(256, 4)
__global__ void gram_kernel(const __hip_bfloat16* __restrict__ xb,
                            const float* __restrict__ sq,
                            const int* __restrict__ tgt,
                            unsigned* __restrict__ ap,
                            unsigned* __restrict__ an, int n) {
    __shared__ __align__(16) __hip_bfloat16 Bs[2][64 * D];

    const int tid  = threadIdx.x;
    const int wid  = tid >> 6;
    const int lane = tid & 63;
    const int quad = lane >> 4;
    const int l    = lane & 15;
    const int i0   = blockIdx.x * 128;
    const int jspan = n / NSPLIT;          // 512
    const int njit  = jspan / 64;          // 8
    const int j0    = blockIdx.y * jspan;
    const int rowbase = i0 + wid * 32;

    // A fragments, register-resident: lane holds A[m=l][k=quad*8+j]
    bf16x8 afrag[2][4];
    {
        const __hip_bfloat16* abase = xb + (size_t)(rowbase + l) * D + quad * 8;
        #pragma unroll
        for (int mt = 0; mt < 2; ++mt)
            #pragma unroll
            for (int ks = 0; ks < 4; ++ks)
                afrag[mt][ks] = *(const bf16x8*)(abase + (size_t)mt * 16 * D + ks * 32);
    }

    int li[2][4];
    #pragma unroll
    for (int mt = 0; mt < 2; ++mt)
        #pragma unroll
        for (int reg = 0; reg < 4; ++reg)
            li[mt][reg] = tgt[rowbase + mt * 16 + quad * 4 + reg];

    float lap[8], lan[8];
    #pragma unroll
    for (int k = 0; k < 8; ++k) { lap[k] = -1e30f; lan[k] = 1e30f; }

    // staging: wave wid owns 16B chunks q = wid*256 + i*64 + lane.
    // LDS chunk q holds global (row r=q>>4, chunk c=(q&15)^(r&15)) of tile.
    // global_load_lds: lds dest = uniform base (q0+i*64)*16 + lane*16 (hw).
    const int q0 = wid * 256;
    const char* xbb = (const char*)xb;

    #define PREFETCH(jt0, buf)                                                \
        do {                                                                  \
            _Pragma("unroll")                                                 \
            for (int i_ = 0; i_ < 4; ++i_) {                                  \
                int q_ = q0 + i_ * 64 + lane;                                 \
                int r_ = q_ >> 4;                                             \
                int c_ = (q_ & 15) ^ (r_ & 15);                               \
                const char* g_ = xbb + (size_t)((jt0) + r_) * 256             \
                                     + (size_t)c_ * 16;                       \
                char* l_ = (char*)&Bs[buf][0] + (size_t)(q0 + i_ * 64) * 16;  \
                __builtin_amdgcn_global_load_lds(                             \
                    (const __attribute__((address_space(1))) void*)g_,        \
                    (__attribute__((address_space(3))) void*)l_, 16, 0, 0);   \
            }                                                                 \
        } while (0)

    PREFETCH(j0, 0);
    __syncthreads();   // drains vmcnt -> tile 0 resident

    for (int jj = 0; jj < njit; ++jj) {
        const int cur = jj & 1;
        if (jj < njit - 1) PREFETCH(j0 + (jj + 1) * 64, cur ^ 1);  // async

        const char* Bb = (const char*)&Bs[cur][0];
        const int jbase = j0 + jj * 64;
        #pragma unroll
        for (int jt = 0; jt < 4; ++jt) {
            f32x4 acc0 = (f32x4){0.f, 0.f, 0.f, 0.f};
            f32x4 acc1 = (f32x4){0.f, 0.f, 0.f, 0.f};
            #pragma unroll
            for (int ks = 0; ks < 4; ++ks) {
                // frag: row jt*16+l, k-chunk ks*4+quad, swizzled
                int q = (jt * 16 + l) * 16 + ((ks * 4 + quad) ^ l);
                bf16x8 bfr = *(const bf16x8*)(Bb + (size_t)q * 16);
                acc0 = __builtin_amdgcn_mfma_f32_16x16x32_bf16(afrag[0][ks], bfr, acc0, 0, 0, 0);
                acc1 = __builtin_amdgcn_mfma_f32_16x16x32_bf16(afrag[1][ks], bfr, acc1, 0, 0, 0);
            }
            float sjc = sq[jbase + jt * 16 + l];
            int   tjc = tgt[jbase + jt * 16 + l];
            #pragma unroll
            for (int reg = 0; reg < 4; ++reg) {
                float t0 = fmaf(-2.0f, acc0[reg], sjc);
                float t1 = fmaf(-2.0f, acc1[reg], sjc);
                bool s0 = (li[0][reg] == tjc);
                bool s1 = (li[1][reg] == tjc);
                lap[reg]     = fmaxf(lap[reg],     s0 ? t0 : -1e30f);
                lan[reg]     = fminf(lan[reg],     s0 ? 1e30f : t0);
                lap[4 + reg] = fmaxf(lap[4 + reg], s1 ? t1 : -1e30f);
                lan[4 + reg] = fminf(lan[4 + reg], s1 ? 1e30f : t1);
            }
        }

        // barrier: (a) drains this iter's prefetch (vmcnt0 before s_barrier),
        // (b) all waves done reading Bs[cur] before next iter's prefetch
        // overwrites it.
        __syncthreads();
    }
    #undef PREFETCH

    // reduce across 16 column-lanes (xor<16 stays within quad group)
    #pragma unroll
    for (int mt = 0; mt < 2; ++mt)
        #pragma unroll
        for (int reg = 0; reg < 4; ++reg) {
            float p = lap[mt * 4 + reg], q = lan[mt * 4 + reg];
            #pragma unroll
            for (int o = 1; o < 16; o <<= 1) {
                p = fmaxf(p, __shfl_xor(p, o, 64));
                q = fminf(q, __shfl_xor(q, o, 64));
            }
            if (l == mt * 4 + reg) {   // one writer lane per quad (lanes 0..7)
                int gi = rowbase + mt * 16 + quad * 4 + reg;
                float s = sq[gi];
                atomicMax(&ap[gi], __float_as_uint(fmaxf(s + p, 0.0f)));
                atomicMin(&an[gi], __float_as_uint(fmaxf(s + q, 0.0f)));
            }
        }
}

// ---------------- final: sum relu(ap - an + margin) ----------------
__global__ void final_kernel(const unsigned* __restrict__ ap,
                             const unsigned* __restrict__ an,
                             float* __restrict__ out, int n) {
    int i = blockIdx.x * blockDim.x + threadIdx.x;
    float v = 0.f;
    if (i < n) {
        float p = __uint_as_float(ap[i]);
        float q = __uint_as_float(an[i]);
        v = fmaxf(p - q + MARGIN, 0.0f);
    }
    #pragma unroll
    for (int o = 32; o > 0; o >>= 1) v += __shfl_xor(v, o, 64);
    __shared__ float ws[4];
    int lane = threadIdx.x & 63, w = threadIdx.x >> 6;
    if (lane == 0) ws[w] = v;
    __syncthreads();
    if (threadIdx.x == 0) atomicAdd(out, ws[0] + ws[1] + ws[2] + ws[3]);
}

extern "C" void kernel_launch(void* const* d_in, const int* in_sizes, int n_in,
                              void* d_out, int out_size, void* d_ws, size_t ws_size,
                              hipStream_t stream) {
    const float* x   = (const float*)d_in[0];
    const int*   tgt = (const int*)d_in[1];
    float* out = (float*)d_out;
    const int n = in_sizes[1];              // 8192

    float*          sq = (float*)d_ws;
    unsigned*       ap = (unsigned*)((char*)d_ws + (size_t)n * 4);
    unsigned*       an = ap + n;
    __hip_bfloat16* xb = (__hip_bfloat16*)((char*)d_ws + (size_t)n * 12);

    prep_kernel<<<n / 4, 256, 0, stream>>>(x, sq, ap, an, xb, out, n);
    dim3 grid(n / 128, NSPLIT);
    gram_kernel<<<grid, 256, 0, stream>>>(xb, sq, tgt, ap, an, n);
    final_kernel<<<n / 256, 256, 0, stream>>>(ap, an, out, n);
}